// Round 1
// 34584.332 us; speedup vs baseline: 1.0646x; 1.0646x over previous
//
#include <hip/hip_runtime.h>
#include <cstdint>
#include <cstddef>

// Problem constants (match reference)
#define N_ITEMS 16384
#define D_STATE 2048
#define D_SEM   1024
#define S_SLOTS 4096
#define DTHRESH 2.0f

#define B_ITEMS 256              // sequential-scan block size
#define NBLK    (N_ITEMS / B_ITEMS)   // 64
#define CHUNK_BLKS 16            // content-GEMM chunking (16 MB buffer)
#define CHUNK_ITEMS (B_ITEMS * CHUNK_BLKS)  // 4096

typedef unsigned long long u64;
typedef unsigned int u32;

// ---------------------------------------------------------------------------
// Content GEMM: C[i,j] = sum_d A[i,d]*W[j,d] + b[j].  64x64 tile, K=2048.
// ---------------------------------------------------------------------------
__global__ __launch_bounds__(256)
void gemm_kernel(const float* __restrict__ A, const float* __restrict__ W,
                 const float* __restrict__ bias, float* __restrict__ C) {
  __shared__ float As[16][68];
  __shared__ float Bs[16][68];
  const int t = threadIdx.x;
  const int ty = t >> 4, tx = t & 15;
  const int i0 = blockIdx.x * 64, j0 = blockIdx.y * 64;
  const int lrow = t >> 2, lcol = (t & 3) << 2;
  float acc[4][4] = {{0.f}};
  const float* ap = A + (size_t)(i0 + lrow) * D_STATE + lcol;
  const float* wp = W + (size_t)(j0 + lrow) * D_STATE + lcol;
  for (int k0 = 0; k0 < D_STATE; k0 += 16) {
    float4 av = *(const float4*)(ap + k0);
    float4 wv = *(const float4*)(wp + k0);
    __syncthreads();
    As[lcol + 0][lrow] = av.x; As[lcol + 1][lrow] = av.y;
    As[lcol + 2][lrow] = av.z; As[lcol + 3][lrow] = av.w;
    Bs[lcol + 0][lrow] = wv.x; Bs[lcol + 1][lrow] = wv.y;
    Bs[lcol + 2][lrow] = wv.z; Bs[lcol + 3][lrow] = wv.w;
    __syncthreads();
#pragma unroll
    for (int kk = 0; kk < 16; kk++) {
      float a[4], b[4];
#pragma unroll
      for (int y = 0; y < 4; y++) a[y] = As[kk][ty * 4 + y];
#pragma unroll
      for (int x = 0; x < 4; x++) b[x] = Bs[kk][tx * 4 + x];
#pragma unroll
      for (int y = 0; y < 4; y++)
#pragma unroll
        for (int x = 0; x < 4; x++) acc[y][x] = fmaf(a[y], b[x], acc[y][x]);
    }
  }
#pragma unroll
  for (int y = 0; y < 4; y++)
#pragma unroll
    for (int x = 0; x < 4; x++) {
      const int col = j0 + tx * 4 + x;
      C[(size_t)(i0 + ty * 4 + y) * D_SEM + col] = acc[y][x] + bias[col];
    }
}

// ---------------------------------------------------------------------------
// Per-chunk block-diagonal Gram: G[z][i][j] = c_i . c_j within block z.
// grid (4,4,CHUNK_BLKS), 64x64 tiles, K=1024.
// ---------------------------------------------------------------------------
__global__ __launch_bounds__(256)
void gram_kernel(const float* __restrict__ Cc, float* __restrict__ G) {
  const int z = blockIdx.z;
  const float* A = Cc + (size_t)z * B_ITEMS * D_SEM;
  __shared__ float As[16][68];
  __shared__ float Bs[16][68];
  const int t = threadIdx.x;
  const int ty = t >> 4, tx = t & 15;
  const int i0 = blockIdx.x * 64, j0 = blockIdx.y * 64;
  const int lrow = t >> 2, lcol = (t & 3) << 2;
  float acc[4][4] = {{0.f}};
  const float* ap = A + (size_t)(i0 + lrow) * D_SEM + lcol;
  const float* wp = A + (size_t)(j0 + lrow) * D_SEM + lcol;
  for (int k0 = 0; k0 < D_SEM; k0 += 16) {
    float4 av = *(const float4*)(ap + k0);
    float4 wv = *(const float4*)(wp + k0);
    __syncthreads();
    As[lcol + 0][lrow] = av.x; As[lcol + 1][lrow] = av.y;
    As[lcol + 2][lrow] = av.z; As[lcol + 3][lrow] = av.w;
    Bs[lcol + 0][lrow] = wv.x; Bs[lcol + 1][lrow] = wv.y;
    Bs[lcol + 2][lrow] = wv.z; Bs[lcol + 3][lrow] = wv.w;
    __syncthreads();
#pragma unroll
    for (int kk = 0; kk < 16; kk++) {
      float a[4], b[4];
#pragma unroll
      for (int y = 0; y < 4; y++) a[y] = As[kk][ty * 4 + y];
#pragma unroll
      for (int x = 0; x < 4; x++) b[x] = Bs[kk][tx * 4 + x];
#pragma unroll
      for (int y = 0; y < 4; y++)
#pragma unroll
        for (int x = 0; x < 4; x++) acc[y][x] = fmaf(a[y], b[x], acc[y][x]);
    }
  }
  float* Gz = G + (size_t)z * B_ITEMS * B_ITEMS;
#pragma unroll
  for (int y = 0; y < 4; y++)
#pragma unroll
    for (int x = 0; x < 4; x++)
      Gz[(size_t)(i0 + ty * 4 + y) * B_ITEMS + j0 + tx * 4 + x] = acc[y][x];
}

// ---------------------------------------------------------------------------
// Per-block dot-product matrix: P[i][s] = c_i . t_s.  Tiles past the
// max-possible-valid limit are zero-filled (keeps P finite everywhere so
// invalid slots can never win the argmin; they are masked by n_reg=+inf in
// the scan).  grid (4, 64).
// ---------------------------------------------------------------------------
__global__ __launch_bounds__(256)
void pgemm_kernel(const float* __restrict__ A,   // content block 256 x 1024
                  const float* __restrict__ T,   // traces (= out) 4096 x 1024
                  float* __restrict__ P,
                  const int* __restrict__ state) {
  const int limit = min(state[0] + B_ITEMS, S_SLOTS);
  const int j0 = blockIdx.y * 64;
  const int i0 = blockIdx.x * 64;
  const int t = threadIdx.x;
  const int ty = t >> 4, tx = t & 15;
  if (j0 >= limit) {
    const float4 z = {0.f, 0.f, 0.f, 0.f};
    const int col = j0 + tx * 4;
#pragma unroll
    for (int y = 0; y < 4; y++)
      *(float4*)(P + (size_t)(i0 + ty * 4 + y) * S_SLOTS + col) = z;
    return;
  }
  __shared__ float As[16][68];
  __shared__ float Bs[16][68];
  const int lrow = t >> 2, lcol = (t & 3) << 2;
  float acc[4][4] = {{0.f}};
  const float* ap = A + (size_t)(i0 + lrow) * D_SEM + lcol;
  const float* wp = T + (size_t)(j0 + lrow) * D_SEM + lcol;
  for (int k0 = 0; k0 < D_SEM; k0 += 16) {
    float4 av = *(const float4*)(ap + k0);
    float4 wv = *(const float4*)(wp + k0);
    __syncthreads();
    As[lcol + 0][lrow] = av.x; As[lcol + 1][lrow] = av.y;
    As[lcol + 2][lrow] = av.z; As[lcol + 3][lrow] = av.w;
    Bs[lcol + 0][lrow] = wv.x; Bs[lcol + 1][lrow] = wv.y;
    Bs[lcol + 2][lrow] = wv.z; Bs[lcol + 3][lrow] = wv.w;
    __syncthreads();
#pragma unroll
    for (int kk = 0; kk < 16; kk++) {
      float a[4], b[4];
#pragma unroll
      for (int y = 0; y < 4; y++) a[y] = As[kk][ty * 4 + y];
#pragma unroll
      for (int x = 0; x < 4; x++) b[x] = Bs[kk][tx * 4 + x];
#pragma unroll
      for (int y = 0; y < 4; y++)
#pragma unroll
        for (int x = 0; x < 4; x++) acc[y][x] = fmaf(a[y], b[x], acc[y][x]);
    }
  }
#pragma unroll
  for (int y = 0; y < 4; y++)
#pragma unroll
    for (int x = 0; x < 4; x++)
      P[(size_t)(i0 + ty * 4 + y) * S_SLOTS + j0 + tx * 4 + x] = acc[y][x];
}

// ---------------------------------------------------------------------------
// init: copy traces0 -> out (working traces), n_g[s] = ||t_s||^2, reset state.
// ---------------------------------------------------------------------------
__global__ __launch_bounds__(256)
void init_kernel(const float* __restrict__ traces0, float* __restrict__ out,
                 float* __restrict__ n_g, int* __restrict__ state) {
  __shared__ float wsum[4];
  const int s = blockIdx.x, t = threadIdx.x;
  const int lane = t & 63, wave = t >> 6;
  float4 v = *(const float4*)(traces0 + (size_t)s * D_SEM + 4 * t);
  *(float4*)(out + (size_t)s * D_SEM + 4 * t) = v;
  float nn = v.x * v.x + v.y * v.y + v.z * v.z + v.w * v.w;
#pragma unroll
  for (int o = 32; o; o >>= 1) nn += __shfl_down(nn, o, 64);
  if (lane == 0) wsum[wave] = nn;
  __syncthreads();
  if (t == 0) n_g[s] = wsum[0] + wsum[1] + wsum[2] + wsum[3];
  if (s == 0 && t == 0) { state[0] = 0; state[1] = 0; }
}

// ---------------------------------------------------------------------------
// Sequential scan over one block of 256 items. SINGLE workgroup, 256 thr.
// P-formulation: thread t owns slots [16t,16t+16): holds P-row slice AND the
// slot norms n_reg (invalid slots = +inf) in registers.  After the argmin
// broadcast, EVERY thread computes the decision redundantly (no serial
// thread-0 phase, no LDS norm array, no published state).  2 barriers/step.
// ---------------------------------------------------------------------------
__global__ __launch_bounds__(256)
void scan_kernel(float* __restrict__ P, const float* __restrict__ Gb,
                 const float* __restrict__ rewards, const float* __restrict__ n_g,
                 int* __restrict__ state, u64* __restrict__ decs) {
  __shared__ u64 partials[2][4];
  const int t = threadIdx.x;          // 0..255
  const int lane = t & 63, wave = t >> 6;
  const int s_base = t << 4;

  int num = state[0];
  int ptr = state[1];

  // per-slot ||t_s||^2 in owner registers; +inf marks invalid
  float n_reg[16];
#pragma unroll
  for (int k = 0; k < 16; k += 4) {
    float4 nv = *(const float4*)(n_g + s_base + k);
    n_reg[k + 0] = (s_base + k + 0 < num) ? nv.x : __uint_as_float(0x7F800000u);
    n_reg[k + 1] = (s_base + k + 1 < num) ? nv.y : __uint_as_float(0x7F800000u);
    n_reg[k + 2] = (s_base + k + 2 < num) ? nv.z : __uint_as_float(0x7F800000u);
    n_reg[k + 3] = (s_base + k + 3 < num) ? nv.w : __uint_as_float(0x7F800000u);
  }

  float p_cur[16], p_nxt[16];
#pragma unroll
  for (int k = 0; k < 16; k += 4) {
    float4 v = *(const float4*)(P + s_base + k);          // row 0
    p_cur[k] = v.x; p_cur[k + 1] = v.y; p_cur[k + 2] = v.z; p_cur[k + 3] = v.w;
  }
#pragma unroll
  for (int k = 0; k < 16; k++) p_nxt[k] = 0.f;

  float greg = Gb[t];        // G[0][t]
  float gi   = Gb[0];        // G[0][0]
  float ri   = rewards[0];

  u32 my_slot = 0; float my_lr = 0.f;   // decision latch: thread t keeps step t

  for (int i = 0; i < B_ITEMS; i++) {
    // --- top: issue all prefetches (uniform + next P row), latency-hidden ---
    float gi_n = 0.f, ri_n = 0.f, gnext = 0.f, greg_n = 0.f;
    if (i + 1 < B_ITEMS) {
      gi_n   = Gb[(size_t)(i + 1) * B_ITEMS + (i + 1)];
      ri_n   = rewards[i + 1];
      gnext  = Gb[(size_t)i * B_ITEMS + (i + 1)];
      greg_n = Gb[(size_t)(i + 1) * B_ITEMS + t];
#pragma unroll
      for (int k = 0; k < 16; k += 4) {
        float4 v = *(const float4*)(P + (size_t)(i + 1) * S_SLOTS + s_base + k);
        p_nxt[k] = v.x; p_nxt[k + 1] = v.y; p_nxt[k + 2] = v.z; p_nxt[k + 3] = v.w;
      }
    }

    // --- keys + wave reduce (argmin of n + gi - 2p; invalid => +inf) ---
    u64 best = ~0ull;
#pragma unroll
    for (int k = 0; k < 16; k++) {
      const float d2 = fmaxf(fmaf(-2.0f, p_cur[k], n_reg[k] + gi), 0.f);
      const u64 key = ((u64)__float_as_uint(d2) << 32) | (u32)(s_base + k);
      if (key < best) best = key;
    }
#pragma unroll
    for (int o = 32; o; o >>= 1) {
      const u64 v = __shfl_down(best, o, 64);
      if (v < best) best = v;
    }
    if (lane == 0) partials[i & 1][wave] = best;
    __syncthreads();

    // --- redundant decision on every thread ---
    u64 bk = partials[i & 1][0];
    { u64 v = partials[i & 1][1]; if (v < bk) bk = v;
      v = partials[i & 1][2]; if (v < bk) bk = v;
      v = partials[i & 1][3]; if (v < bk) bk = v; }
    const float d2b = __uint_as_float((u32)(bk >> 32));
    const int nslot = (int)(u32)bk;
    const bool upd = (num > 0) && (sqrtf(d2b) < DTHRESH);
    const float lr = __fmul_rn(0.01f, __fadd_rn(1.0f, fabsf(ri)));
    const int slot = upd ? nslot : ptr;
    const float omr = 1.0f - lr;
    if (!upd) { num = min(num + 1, S_SLOTS); ptr = (ptr + 1) & (S_SLOTS - 1); }
    if (i == t) { my_slot = (u32)slot | (upd ? 0x80000000u : 0u); my_lr = lr; }

    // --- owner: norm recurrence + register fixup of row i+1 ---
    if ((slot >> 4) == t) {
#define OWNFIX(K) { const float nold = n_reg[K]; float pn = p_nxt[K]; float nnew; \
      if (upd) { const float pc = 0.5f * (nold + gi - d2b); \
        nnew = omr * omr * nold + 2.0f * lr * omr * pc + lr * lr * gi; \
        pn = fmaf(omr, pn, lr * gnext); } \
      else { nnew = gi; pn = gnext; } \
      n_reg[K] = nnew; p_nxt[K] = pn; }
      switch (slot & 15) {
        case 0:  OWNFIX(0)  break; case 1:  OWNFIX(1)  break;
        case 2:  OWNFIX(2)  break; case 3:  OWNFIX(3)  break;
        case 4:  OWNFIX(4)  break; case 5:  OWNFIX(5)  break;
        case 6:  OWNFIX(6)  break; case 7:  OWNFIX(7)  break;
        case 8:  OWNFIX(8)  break; case 9:  OWNFIX(9)  break;
        case 10: OWNFIX(10) break; case 11: OWNFIX(11) break;
        case 12: OWNFIX(12) break; case 13: OWNFIX(13) break;
        case 14: OWNFIX(14) break; default: OWNFIX(15) break;
      }
#undef OWNFIX
    }

    // --- global RMW of the decided column for rows i+2..255 ---
    if (t >= i + 2) {
      float* qp = P + (size_t)t * S_SLOTS + slot;
      if (upd) *qp = fmaf(omr, *qp, __fmul_rn(lr, greg));
      else     *qp = greg;
    }

    // --- rotate ---
#pragma unroll
    for (int k = 0; k < 16; k++) p_cur[k] = p_nxt[k];
    gi = gi_n; ri = ri_n; greg = greg_n;
    __syncthreads();   // drains RMW stores before next step's prefetch
  }

  if (t == 0) { state[0] = num; state[1] = ptr; }
  decs[t] = ((u64)__float_as_uint(my_lr) << 32) | (u64)my_slot;
}

// ---------------------------------------------------------------------------
// apply: materialize the block's trace mutations. WG j owns slot_j iff step j
// is the LAST step touching it. Composition: t = alpha*t_snap + sum beta_j c_j.
// Recomputes exact ||t||^2 -> n_g (bounds numeric drift to one block).
// ---------------------------------------------------------------------------
__global__ __launch_bounds__(256)
void apply_kernel(const float* __restrict__ content,  // block 256 x 1024
                  const u64* __restrict__ decs,       // 256 decisions
                  float* __restrict__ traces,         // = out
                  float* __restrict__ n_g) {
  __shared__ u32 aslot[B_ITEMS];
  __shared__ float alr[B_ITEMS];
  __shared__ float betas[B_ITEMS];
  __shared__ int notowner;
  __shared__ float wsum[4];
  const int t = threadIdx.x, j = blockIdx.x;
  const int lane = t & 63, wave = t >> 6;
  const u64 d = decs[t];
  aslot[t] = (u32)(d & 0xFFFFFFFFull);
  alr[t] = __uint_as_float((u32)(d >> 32));
  if (t == 0) notowner = 0;
  __syncthreads();
  const u32 myslot = aslot[j] & 0x7FFFFFFFu;
  if (t > j && (aslot[t] & 0x7FFFFFFFu) == myslot) notowner = 1;
  __syncthreads();
  if (notowner) return;

  float alpha = 1.f, beta = 0.f;
  for (int k = 0; k < B_ITEMS; k++) {
    const u32 a = aslot[k];
    if ((a & 0x7FFFFFFFu) == myslot) {
      const float lr = alr[k];
      if (a & 0x80000000u) {           // update
        const float om = 1.f - lr;
        alpha *= om; beta *= om;
        if (t == k) beta += lr;
      } else {                         // insert
        alpha = 0.f; beta = (t == k) ? 1.f : 0.f;
      }
    }
  }
  betas[t] = beta;
  __syncthreads();

  float4 v = *(const float4*)(traces + (size_t)myslot * D_SEM + 4 * t);
  v.x *= alpha; v.y *= alpha; v.z *= alpha; v.w *= alpha;
  for (int k = 0; k < B_ITEMS; k++) {
    if ((aslot[k] & 0x7FFFFFFFu) == myslot) {
      const float bk = betas[k];
      const float4 c = *(const float4*)(content + (size_t)k * D_SEM + 4 * t);
      v.x = fmaf(bk, c.x, v.x); v.y = fmaf(bk, c.y, v.y);
      v.z = fmaf(bk, c.z, v.z); v.w = fmaf(bk, c.w, v.w);
    }
  }
  *(float4*)(traces + (size_t)myslot * D_SEM + 4 * t) = v;
  float nn = v.x * v.x + v.y * v.y + v.z * v.z + v.w * v.w;
#pragma unroll
  for (int o = 32; o; o >>= 1) nn += __shfl_down(nn, o, 64);
  if (lane == 0) wsum[wave] = nn;
  __syncthreads();
  if (t == 0) n_g[myslot] = wsum[0] + wsum[1] + wsum[2] + wsum[3];
}

// ---------------------------------------------------------------------------
// finalize: parallel strengths replay via two-pass LDS histogram.
// Per slot: final strength = 1 + (#updates after last insert) if ever
// inserted, else strengths0 + #updates.  Then masked mean + scalars.
// ---------------------------------------------------------------------------
__global__ __launch_bounds__(256)
void finalize_kernel(const float* __restrict__ strengths0,
                     const u64* __restrict__ decs,
                     const int* __restrict__ state, float* __restrict__ out) {
  __shared__ int last_ins[S_SLOTS];
  __shared__ int cnt[S_SLOTS];
  __shared__ float wsum[4];
  const int t = threadIdx.x, lane = t & 63, wave = t >> 6;
  for (int s = t; s < S_SLOTS; s += 256) { last_ins[s] = -1; cnt[s] = 0; }
  __syncthreads();
  // pass 1: last insert index per slot
  for (int k = t; k < N_ITEMS; k += 256) {
    const u32 dd = (u32)(decs[k] & 0xFFFFFFFFull);
    if (!(dd & 0x80000000u)) atomicMax(&last_ins[(int)dd], k);
  }
  __syncthreads();
  // pass 2: count updates after the last insert
  for (int k = t; k < N_ITEMS; k += 256) {
    const u32 dd = (u32)(decs[k] & 0xFFFFFFFFull);
    const int slot = (int)(dd & 0x7FFFFFFFu);
    if ((dd & 0x80000000u) && k > last_ins[slot]) atomicAdd(&cnt[slot], 1);
  }
  __syncthreads();
  const int num = state[0];
  float* outs = out + (size_t)S_SLOTS * D_SEM;
  float lsum = 0.f;
  for (int s = t; s < S_SLOTS; s += 256) {
    const float base = (last_ins[s] >= 0) ? 1.f : strengths0[s];
    const float v = base + (float)cnt[s];
    outs[s] = v;
    if (s < num) lsum += v;
  }
#pragma unroll
  for (int o = 32; o; o >>= 1) lsum += __shfl_down(lsum, o, 64);
  if (lane == 0) wsum[wave] = lsum;
  __syncthreads();
  if (t == 0) {
    const float total = wsum[0] + wsum[1] + wsum[2] + wsum[3];
    float denom = (float)num;
    if (denom < 1.f) denom = 1.f;
    outs[S_SLOTS + 0] = (float)num;
    outs[S_SLOTS + 1] = (float)N_ITEMS;
    outs[S_SLOTS + 2] = (num > 0) ? (total / denom) : 0.f;
  }
}

// ---------------------------------------------------------------------------
extern "C" void kernel_launch(void* const* d_in, const int* in_sizes, int n_in,
                              void* d_out, int out_size, void* d_ws, size_t ws_size,
                              hipStream_t stream) {
  const float* states  = (const float*)d_in[0];
  const float* rewards = (const float*)d_in[1];
  const float* W       = (const float*)d_in[2];
  const float* bias    = (const float*)d_in[3];
  const float* traces0 = (const float*)d_in[4];
  const float* str0    = (const float*)d_in[5];
  float* out = (float*)d_out;   // traces live here (working + final)

  // ws layout (~24.5 MB): content chunk 16MB | P 4MB | Gram 4MB | n_g | decs | state
  char* p = (char*)d_ws;
  float* cbuf = (float*)p;                 p += (size_t)CHUNK_ITEMS * D_SEM * 4;
  float* P    = (float*)p;                 p += (size_t)B_ITEMS * S_SLOTS * 4;
  float* Gb   = (float*)p;                 p += (size_t)CHUNK_BLKS * B_ITEMS * B_ITEMS * 4;
  float* n_g  = (float*)p;                 p += (size_t)S_SLOTS * 4;
  u64*   decs = (u64*)p;                   p += (size_t)N_ITEMS * 8;
  int*   state = (int*)p;

  init_kernel<<<S_SLOTS, 256, 0, stream>>>(traces0, out, n_g, state);

  for (int c = 0; c < N_ITEMS / CHUNK_ITEMS; c++) {
    gemm_kernel<<<dim3(CHUNK_ITEMS / 64, D_SEM / 64), 256, 0, stream>>>(
        states + (size_t)c * CHUNK_ITEMS * D_STATE, W, bias, cbuf);
    gram_kernel<<<dim3(4, 4, CHUNK_BLKS), 256, 0, stream>>>(cbuf, Gb);
    for (int bb = 0; bb < CHUNK_BLKS; bb++) {
      const int b = c * CHUNK_BLKS + bb;
      const float* cblk = cbuf + (size_t)bb * B_ITEMS * D_SEM;
      const float* Gblk = Gb + (size_t)bb * B_ITEMS * B_ITEMS;
      pgemm_kernel<<<dim3(4, S_SLOTS / 64), 256, 0, stream>>>(cblk, out, P, state);
      scan_kernel<<<1, 256, 0, stream>>>(P, Gblk, rewards + (size_t)b * B_ITEMS,
                                         n_g, state, decs + (size_t)b * B_ITEMS);
      apply_kernel<<<B_ITEMS, 256, 0, stream>>>(cblk, decs + (size_t)b * B_ITEMS,
                                                out, n_g);
    }
  }
  finalize_kernel<<<1, 256, 0, stream>>>(str0, decs, state, out);
}